// Round 1
// baseline (816.111 us; speedup 1.0000x reference)
//
#include <hip/hip_runtime.h>
#include <hip/hip_bf16.h>
#include <cstdint>
#include <cstddef>

typedef __bf16 bf16_t;
typedef __bf16 bf16x8 __attribute__((ext_vector_type(8)));
typedef __bf16 bf16x4 __attribute__((ext_vector_type(4)));
typedef float  f32x4  __attribute__((ext_vector_type(4)));

static constexpr int Bb = 4, Ss = 1024, Ee = 1024, Hh = 32, Dd = 32;
static constexpr int Ntok = Bb * Ss;   // 4096
static constexpr int E3   = 3 * Ee;    // 3072
static constexpr float SCALE = 0.17677669529663687f; // 1/sqrt(32)

__device__ __forceinline__ void gl_lds16(const void* g, void* l) {
  // async global->LDS, 16B per lane; LDS dest = wave-uniform base + lane*16
  __builtin_amdgcn_global_load_lds(
      (const __attribute__((address_space(1))) void*)g,
      (__attribute__((address_space(3))) void*)l, 16, 0, 0);
}

// ---------------------------------------------------------------- cvt f32->bf16
__global__ __launch_bounds__(256) void f32_to_bf16_k(const float* __restrict__ in,
                                                     bf16_t* __restrict__ out, int n4) {
  const int i = blockIdx.x * 256 + threadIdx.x;
  if (i < n4) {
    const float4 v = *(const float4*)(in + (size_t)i * 4);
    bf16x4 o = {(bf16_t)v.x, (bf16_t)v.y, (bf16_t)v.z, (bf16_t)v.w};
    *(bf16x4*)(out + (size_t)i * 4) = o;
  }
}

// ---------------------------------------------------------------- mean over S
__global__ __launch_bounds__(256) void colmean_part(const float* __restrict__ x,
                                                    float* __restrict__ part) {
  const int b = blockIdx.y, sc = blockIdx.x;           // sc in 0..31, 32 rows each
  const float* base = x + ((size_t)b * Ss + sc * 32) * Ee;
  for (int k = 0; k < 4; ++k) {
    const int e = threadIdx.x + k * 256;
    float s = 0.f;
    for (int i = 0; i < 32; ++i) s += base[(size_t)i * Ee + e];
    part[((size_t)sc * 4 + b) * Ee + e] = s;
  }
}
__global__ __launch_bounds__(256) void colmean_fin(const float* __restrict__ part,
                                                   float* __restrict__ xm) {
  const int idx = blockIdx.x * 256 + threadIdx.x;      // 0..4095
  const int b = idx >> 10, e = idx & 1023;
  float s = 0.f;
  for (int sc = 0; sc < 32; ++sc) s += part[((size_t)sc * 4 + b) * Ee + e];
  xm[idx] = s * (1.0f / 1024.0f);
}

// ---------------------------------------------------------------- h = relu(xmean @ w1^T + b1)
__global__ __launch_bounds__(256) void hgemm(const float* __restrict__ xm,
                                             const float* __restrict__ w1,
                                             const float* __restrict__ b1,
                                             float* __restrict__ hout) {
  __shared__ float xl[4 * 1024];
  for (int i = threadIdx.x; i < 4096; i += 256) xl[i] = xm[i];
  __syncthreads();
  const int j = blockIdx.x * 64 + (threadIdx.x >> 2);
  const int b = threadIdx.x & 3;
  const float* wr = w1 + (size_t)j * Ee;
  const float* xr = xl + b * 1024;
  float s = 0.f;
  for (int e = 0; e < 1024; ++e) s += xr[e] * wr[e];
  s += b1[j];
  hout[b * 1024 + j] = fmaxf(s, 0.f);
}

// ---------------------------------------------------------------- phase = cos(h @ w2^T + b2)
__global__ __launch_bounds__(128) void phasek(const float* __restrict__ hin,
                                              const float* __restrict__ w2,
                                              const float* __restrict__ b2,
                                              float* __restrict__ ph) {
  const int t = threadIdx.x;          // 128 threads: b = t>>5, hh = t&31
  const int b = t >> 5, hh = t & 31;
  const float* hr = hin + b * 1024;
  const float* wr = w2 + (size_t)hh * Ee;
  float s = 0.f;
  for (int j = 0; j < 1024; ++j) s += hr[j] * wr[j];
  ph[t] = cosf(s + b2[hh]);
}

// ---------------------------------------------------------------- GEMM: C = A @ Bt^T + bias (+epilogue)
// MODE 0: store bf16 | 1: *phase[b,head] then bf16 | 2: +resid then bf16 | 3: store fp32
template <int MODE>
__global__ __launch_bounds__(256) void gemm_bt(const bf16_t* __restrict__ A,
                                               const bf16_t* __restrict__ Bt,
                                               const float* __restrict__ bias,
                                               void* __restrict__ Cout,
                                               const float* __restrict__ phase,
                                               const bf16_t* __restrict__ resid,
                                               int K, int lda, int ldb, int ldc) {
  __shared__ bf16_t As[128 * 32];
  __shared__ bf16_t Bs[128 * 32];
  const int tid = threadIdx.x;
  const int w = tid >> 6, lane = tid & 63;
  const int m0 = blockIdx.y * 128, n0 = blockIdx.x * 128;
  const int wr = (w >> 1) * 64, wc = (w & 1) * 64;
  const int r_ld = lane >> 2, c_ld = (lane & 3) * 8;
  const int rr = lane & 15, kk8 = (lane >> 4) * 8;
  f32x4 acc[4][4];
#pragma unroll
  for (int m = 0; m < 4; ++m)
#pragma unroll
    for (int n = 0; n < 4; ++n) acc[m][n] = f32x4{0.f, 0.f, 0.f, 0.f};

  for (int kt = 0; kt < K; kt += 32) {
#pragma unroll
    for (int j = 0; j < 2; ++j) {
      const int r0 = w * 16 + j * 64;
      gl_lds16(A + (size_t)(m0 + r0 + r_ld) * lda + kt + c_ld, &As[r0 * 32]);
      gl_lds16(Bt + (size_t)(n0 + r0 + r_ld) * ldb + kt + c_ld, &Bs[r0 * 32]);
    }
    __syncthreads();
    bf16x8 af[4], bfr[4];
#pragma unroll
    for (int m = 0; m < 4; ++m) af[m] = *(const bf16x8*)&As[(wr + m * 16 + rr) * 32 + kk8];
#pragma unroll
    for (int n = 0; n < 4; ++n) bfr[n] = *(const bf16x8*)&Bs[(wc + n * 16 + rr) * 32 + kk8];
#pragma unroll
    for (int m = 0; m < 4; ++m)
#pragma unroll
      for (int n = 0; n < 4; ++n)
        acc[m][n] = __builtin_amdgcn_mfma_f32_16x16x32_bf16(af[m], bfr[n], acc[m][n], 0, 0, 0);
    __syncthreads();
  }

  const int rr4 = (lane >> 4) * 4, cc = lane & 15;
#pragma unroll
  for (int m = 0; m < 4; ++m) {
#pragma unroll
    for (int n = 0; n < 4; ++n) {
      const int gr0 = m0 + wr + m * 16 + rr4;
      const int gc = n0 + wc + n * 16 + cc;
      const float bb = bias[gc];
#pragma unroll
      for (int i = 0; i < 4; ++i) {
        const size_t idx = (size_t)(gr0 + i) * ldc + gc;
        float v = acc[m][n][i] + bb;
        if constexpr (MODE == 1) v *= phase[(((gr0 + i) >> 10) << 5) + (gc >> 5)];
        if constexpr (MODE == 2) v += (float)resid[idx];
        if constexpr (MODE == 3) ((float*)Cout)[idx] = v;
        else ((bf16_t*)Cout)[idx] = (bf16_t)v;
      }
    }
  }
}

// ---------------------------------------------------------------- scores + softmax -> P
// Block: 256 thr (4 waves x 16 q-rows), one (bh, 64-row tile). Two-pass online softmax.
// K staged in LDS as [4 kplanes][1024 keys][8] -> conflict-free b128 fragment reads.
template <int BF16OUT>
__global__ __launch_bounds__(256) void attn_scores(const bf16_t* __restrict__ Qm,
                                                   const bf16_t* __restrict__ Km, int rs,
                                                   void* __restrict__ Pout, float scale,
                                                   int bh0) {
  __shared__ bf16_t Kl[4 * 1024 * 8];   // 64KB
  const int tid = threadIdx.x, lane = tid & 63, w = tid >> 6;
  const int bh = bh0 + blockIdx.y, b = bh >> 5, h = bh & 31;
  const bf16_t* Kbase = Km + (size_t)b * Ss * rs + h * 32;
  for (int c = tid; c < 4096; c += 256) {
    const int row = c >> 2, g = c & 3;
    *(uint4*)&Kl[(size_t)(g * 1024 + row) * 8] = *(const uint4*)(Kbase + (size_t)row * rs + g * 8);
  }
  const int qrow0 = blockIdx.x * 64 + w * 16;
  const bf16_t* Qbase = Qm + (size_t)b * Ss * rs + h * 32;
  const bf16x8 af = *(const bf16x8*)(Qbase + (size_t)(qrow0 + (lane & 15)) * rs + (lane >> 4) * 8);
  __syncthreads();

  float mrow[4], lrow[4];
#pragma unroll
  for (int i = 0; i < 4; ++i) { mrow[i] = -1e30f; lrow[i] = 0.f; }
  const f32x4 zero = {0.f, 0.f, 0.f, 0.f};

  for (int kt = 0; kt < 16; ++kt) {
    f32x4 s[4];
#pragma unroll
    for (int n = 0; n < 4; ++n) {
      const int key = kt * 64 + n * 16 + (lane & 15);
      const bf16x8 bfr = *(const bf16x8*)&Kl[(size_t)((lane >> 4) * 1024 + key) * 8];
      s[n] = __builtin_amdgcn_mfma_f32_16x16x32_bf16(af, bfr, zero, 0, 0, 0);
    }
#pragma unroll
    for (int n = 0; n < 4; ++n)
#pragma unroll
      for (int i = 0; i < 4; ++i) s[n][i] *= scale;
#pragma unroll
    for (int i = 0; i < 4; ++i) {
      float tm = fmaxf(fmaxf(s[0][i], s[1][i]), fmaxf(s[2][i], s[3][i]));
      tm = fmaxf(tm, __shfl_xor(tm, 1));
      tm = fmaxf(tm, __shfl_xor(tm, 2));
      tm = fmaxf(tm, __shfl_xor(tm, 4));
      tm = fmaxf(tm, __shfl_xor(tm, 8));
      const float nm = fmaxf(mrow[i], tm);
      float ps = __expf(s[0][i] - nm) + __expf(s[1][i] - nm) +
                 __expf(s[2][i] - nm) + __expf(s[3][i] - nm);
      ps += __shfl_xor(ps, 1);
      ps += __shfl_xor(ps, 2);
      ps += __shfl_xor(ps, 4);
      ps += __shfl_xor(ps, 8);
      lrow[i] = lrow[i] * __expf(mrow[i] - nm) + ps;
      mrow[i] = nm;
    }
  }
  float rinv[4];
#pragma unroll
  for (int i = 0; i < 4; ++i) rinv[i] = 1.0f / lrow[i];

  const size_t pb = (size_t)blockIdx.y * Ss * Ss;
  for (int kt = 0; kt < 16; ++kt) {
    f32x4 s[4];
#pragma unroll
    for (int n = 0; n < 4; ++n) {
      const int key = kt * 64 + n * 16 + (lane & 15);
      const bf16x8 bfr = *(const bf16x8*)&Kl[(size_t)((lane >> 4) * 1024 + key) * 8];
      s[n] = __builtin_amdgcn_mfma_f32_16x16x32_bf16(af, bfr, zero, 0, 0, 0);
    }
#pragma unroll
    for (int n = 0; n < 4; ++n)
#pragma unroll
      for (int i = 0; i < 4; ++i) s[n][i] *= scale;
#pragma unroll
    for (int n = 0; n < 4; ++n) {
      const int key = kt * 64 + n * 16 + (lane & 15);
#pragma unroll
      for (int i = 0; i < 4; ++i) {
        const int q = qrow0 + (lane >> 4) * 4 + i;
        const float p = __expf(s[n][i] - mrow[i]) * rinv[i];
        if constexpr (BF16OUT) ((bf16_t*)Pout)[pb + (size_t)q * Ss + key] = (bf16_t)p;
        else ((float*)Pout)[pb + (size_t)q * Ss + key] = p;
      }
    }
  }
}

// ---------------------------------------------------------------- PV: ctx = P @ V  (Vt staged in LDS, padded)
template <int PBF16>
__global__ __launch_bounds__(256) void attn_pv(const void* __restrict__ P,
                                               const bf16_t* __restrict__ Vt,
                                               bf16_t* __restrict__ ctx, int bh0) {
  __shared__ bf16_t vt[32 * 1032];  // rows padded to 1032 elems (2064B, 16B-mult)
  const int tid = threadIdx.x, lane = tid & 63, w = tid >> 6;
  const int bh = bh0 + blockIdx.y, b = bh >> 5, h = bh & 31;
  const bf16_t* vsrc = Vt + (size_t)bh * (Dd * Ss);
  for (int c = tid; c < 4096; c += 256) {
    const int row = c >> 7, col = c & 127;
    *(uint4*)&vt[row * 1032 + col * 8] = *(const uint4*)(vsrc + (size_t)row * Ss + col * 8);
  }
  __syncthreads();
  const int qrow0 = blockIdx.x * 64 + w * 16;
  f32x4 acc[2] = {f32x4{0.f, 0.f, 0.f, 0.f}, f32x4{0.f, 0.f, 0.f, 0.f}};
  const size_t prow = ((size_t)blockIdx.y * Ss + qrow0 + (lane & 15)) * Ss;
  for (int k0 = 0; k0 < 1024; k0 += 32) {
    const int kk = k0 + (lane >> 4) * 8;
    bf16x8 af;
    if constexpr (PBF16) {
      af = *(const bf16x8*)((const bf16_t*)P + prow + kk);
    } else {
      const float* pf = (const float*)P + prow + kk;
      const float4 p0 = *(const float4*)pf;
      const float4 p1 = *(const float4*)(pf + 4);
      af = bf16x8{(bf16_t)p0.x, (bf16_t)p0.y, (bf16_t)p0.z, (bf16_t)p0.w,
                  (bf16_t)p1.x, (bf16_t)p1.y, (bf16_t)p1.z, (bf16_t)p1.w};
    }
#pragma unroll
    for (int n = 0; n < 2; ++n) {
      const bf16x8 bfr = *(const bf16x8*)&vt[(n * 16 + (lane & 15)) * 1032 + kk];
      acc[n] = __builtin_amdgcn_mfma_f32_16x16x32_bf16(af, bfr, acc[n], 0, 0, 0);
    }
  }
#pragma unroll
  for (int n = 0; n < 2; ++n)
#pragma unroll
    for (int i = 0; i < 4; ++i) {
      const int q = qrow0 + (lane >> 4) * 4 + i;
      ctx[((size_t)b * Ss + q) * Ee + h * 32 + n * 16 + (lane & 15)] = (bf16_t)acc[n][i];
    }
}

// ---------------------------------------------------------------- V transpose: [token, e] -> [bh][d][s]
__global__ __launch_bounds__(256) void transpose_v(const bf16_t* __restrict__ src, int rs,
                                                   bf16_t* __restrict__ dst) {
  __shared__ bf16_t buf[128 * 33];
  const int bh = blockIdx.y, b = bh >> 5, h = bh & 31;
  const int s0 = blockIdx.x * 128;
  const bf16_t* in = src + ((size_t)b * Ss + s0) * rs + h * 32;
  for (int e = threadIdx.x; e < 128 * 32; e += 256) {
    const int s = e >> 5, d = e & 31;
    buf[s * 33 + d] = in[(size_t)s * rs + d];
  }
  __syncthreads();
  bf16_t* out = dst + (size_t)bh * (Dd * Ss) + s0;
  for (int e = threadIdx.x; e < 128 * 32; e += 256) {
    const int d = e >> 7, s = e & 127;
    out[(size_t)d * Ss + s] = buf[s * 33 + d];
  }
}

// ================================================================ launcher
extern "C" void kernel_launch(void* const* d_in, const int* in_sizes, int n_in,
                              void* d_out, int out_size, void* d_ws, size_t ws_size,
                              hipStream_t stream) {
  const float* x     = (const float*)d_in[0];
  const float* q_w   = (const float*)d_in[1];
  const float* q_b   = (const float*)d_in[2];
  const float* k_w   = (const float*)d_in[3];
  const float* k_b   = (const float*)d_in[4];
  const float* v_w   = (const float*)d_in[5];
  const float* v_b   = (const float*)d_in[6];
  const float* ph_w1 = (const float*)d_in[7];
  const float* ph_b1 = (const float*)d_in[8];
  const float* ph_w2 = (const float*)d_in[9];
  const float* ph_b2 = (const float*)d_in[10];
  const float* in_w  = (const float*)d_in[11];
  const float* in_b  = (const float*)d_in[12];
  const float* out_w = (const float*)d_in[13];
  const float* out_b = (const float*)d_in[14];
  const float* fin_w = (const float*)d_in[15];
  const float* fin_b = (const float*)d_in[16];

  float* outp = (float*)d_out;
  float* attn_out = outp + (size_t)Ntok * Ee;   // attn_weights region (B,H,S,S) fp32

  char* ws = (char*)d_ws;
  size_t off = 0;
  auto alloc = [&](size_t bytes) -> void* {
    void* p = ws + off;
    off += (bytes + 255) & ~(size_t)255;
    return p;
  };
  bf16_t* x_bf = (bf16_t*)alloc((size_t)Ntok * Ee * 2);
  bf16_t* wq   = (bf16_t*)alloc((size_t)Ee * Ee * 2);
  bf16_t* wk   = (bf16_t*)alloc((size_t)Ee * Ee * 2);
  bf16_t* wv   = (bf16_t*)alloc((size_t)Ee * Ee * 2);
  bf16_t* win  = (bf16_t*)alloc((size_t)E3 * Ee * 2);
  bf16_t* wout = (bf16_t*)alloc((size_t)Ee * Ee * 2);
  bf16_t* wfin = (bf16_t*)alloc((size_t)Ee * Ee * 2);
  bf16_t* Qb   = (bf16_t*)alloc((size_t)Ntok * Ee * 2);
  bf16_t* Kb   = (bf16_t*)alloc((size_t)Ntok * Ee * 2);
  bf16_t* Vb   = (bf16_t*)alloc((size_t)Ntok * Ee * 2);
  bf16_t* Vt   = (bf16_t*)alloc((size_t)Bb * Hh * Dd * Ss * 2);
  bf16_t* ctx  = (bf16_t*)alloc((size_t)Ntok * Ee * 2);
  bf16_t* qkv2 = (bf16_t*)alloc((size_t)Ntok * E3 * 2);
  bf16_t* v2t  = (bf16_t*)alloc((size_t)Bb * Hh * Dd * Ss * 2);
  bf16_t* ctx2 = (bf16_t*)alloc((size_t)Ntok * Ee * 2);
  bf16_t* yb   = (bf16_t*)alloc((size_t)Ntok * Ee * 2);
  float* part  = (float*)alloc((size_t)32 * 4 * 1024 * 4);
  float* xmean = (float*)alloc(4096 * 4);
  float* hb    = (float*)alloc(4096 * 4);
  float* phase = (float*)alloc(128 * 4);

  // adaptive P2 chunk (attention-2 probs, bf16): prefer 32 heads (64MB)
  int HPC = 2;
  if (off + (size_t)32 * Ss * Ss * 2 <= ws_size) HPC = 32;
  else if (off + (size_t)8 * Ss * Ss * 2 <= ws_size) HPC = 8;
  bf16_t* P2 = (bf16_t*)(ws + off);

  // --- conversions to bf16
  f32_to_bf16_k<<<4096, 256, 0, stream>>>(x, x_bf, Ntok * Ee / 4);
  f32_to_bf16_k<<<1024, 256, 0, stream>>>(q_w, wq, Ee * Ee / 4);
  f32_to_bf16_k<<<1024, 256, 0, stream>>>(k_w, wk, Ee * Ee / 4);
  f32_to_bf16_k<<<1024, 256, 0, stream>>>(v_w, wv, Ee * Ee / 4);
  f32_to_bf16_k<<<3072, 256, 0, stream>>>(in_w, win, E3 * Ee / 4);
  f32_to_bf16_k<<<1024, 256, 0, stream>>>(out_w, wout, Ee * Ee / 4);
  f32_to_bf16_k<<<1024, 256, 0, stream>>>(fin_w, wfin, Ee * Ee / 4);

  // --- phase chain (fp32)
  colmean_part<<<dim3(32, 4), 256, 0, stream>>>(x, part);
  colmean_fin<<<16, 256, 0, stream>>>(part, xmean);
  hgemm<<<16, 256, 0, stream>>>(xmean, ph_w1, ph_b1, hb);
  phasek<<<1, 128, 0, stream>>>(hb, ph_w2, ph_b2, phase);

  // --- projections (Q,K get phase fused in epilogue)
  gemm_bt<1><<<dim3(8, 32), 256, 0, stream>>>(x_bf, wq, q_b, Qb, phase, nullptr, 1024, Ee, Ee, Ee);
  gemm_bt<1><<<dim3(8, 32), 256, 0, stream>>>(x_bf, wk, k_b, Kb, phase, nullptr, 1024, Ee, Ee, Ee);
  gemm_bt<0><<<dim3(8, 32), 256, 0, stream>>>(x_bf, wv, v_b, Vb, nullptr, nullptr, 1024, Ee, Ee, Ee);
  transpose_v<<<dim3(8, 128), 256, 0, stream>>>(Vb, Ee, Vt);

  // --- attention 1: P -> d_out (fp32, required output), then PV reads it back
  attn_scores<0><<<dim3(16, 128), 256, 0, stream>>>(Qb, Kb, Ee, attn_out, SCALE, 0);
  attn_pv<0><<<dim3(16, 128), 256, 0, stream>>>(attn_out, Vt, ctx, 0);

  // --- MHA on context
  gemm_bt<0><<<dim3(24, 32), 256, 0, stream>>>(ctx, win, in_b, qkv2, nullptr, nullptr, 1024, Ee, Ee, E3);
  transpose_v<<<dim3(8, 128), 256, 0, stream>>>(qkv2 + 2048, E3, v2t);
  for (int c = 0; c < 128; c += HPC) {
    attn_scores<1><<<dim3(16, HPC), 256, 0, stream>>>(qkv2, qkv2 + 1024, E3, P2, SCALE, c);
    attn_pv<1><<<dim3(16, HPC), 256, 0, stream>>>(P2, v2t, ctx2, c);
  }

  // --- out_proj with fused residual add:  yb = ctx2@out_w^T + out_b + ctx
  gemm_bt<2><<<dim3(8, 32), 256, 0, stream>>>(ctx2, wout, out_b, yb, nullptr, ctx, 1024, Ee, Ee, Ee);
  // --- final:  outp = yb@fin_w^T + fin_b  (fp32 out)
  gemm_bt<3><<<dim3(8, 32), 256, 0, stream>>>(yb, wfin, fin_b, outp, nullptr, nullptr, 1024, Ee, Ee, Ee);
}

// Round 2
// 579.322 us; speedup vs baseline: 1.4087x; 1.4087x over previous
//
#include <hip/hip_runtime.h>
#include <hip/hip_bf16.h>
#include <cstdint>
#include <cstddef>

typedef __bf16 bf16_t;
typedef __bf16 bf16x8 __attribute__((ext_vector_type(8)));
typedef __bf16 bf16x4 __attribute__((ext_vector_type(4)));
typedef float  f32x4  __attribute__((ext_vector_type(4)));

static constexpr int Bb = 4, Ss = 1024, Ee = 1024, Hh = 32, Dd = 32;
static constexpr int Ntok = Bb * Ss;   // 4096
static constexpr int E3   = 3 * Ee;    // 3072
static constexpr float SCALE = 0.17677669529663687f; // 1/sqrt(32)

__device__ __forceinline__ void gl_lds16(const void* g, void* l) {
  __builtin_amdgcn_global_load_lds(
      (const __attribute__((address_space(1))) void*)g,
      (__attribute__((address_space(3))) void*)l, 16, 0, 0);
}

// ---------------------------------------------------------------- fused f32->bf16 conversions
// regions (in f32x4 units): x 1048576 | qw 262144 | kw 262144 | vw 262144 | inw 786432 | ow 262144 | fw 262144
__global__ __launch_bounds__(256) void conv_all(const float* __restrict__ x,  const float* __restrict__ qw,
                                                const float* __restrict__ kw, const float* __restrict__ vw,
                                                const float* __restrict__ inw,const float* __restrict__ ow,
                                                const float* __restrict__ fw,
                                                bf16_t* xb, bf16_t* qb, bf16_t* kb, bf16_t* vb,
                                                bf16_t* inb, bf16_t* ob, bf16_t* fb) {
  const int i = blockIdx.x * 256 + threadIdx.x;
  const float* src; bf16_t* dst; int base;
  if      (i < 1048576) { src = x;   dst = xb;  base = 0; }
  else if (i < 1310720) { src = qw;  dst = qb;  base = 1048576; }
  else if (i < 1572864) { src = kw;  dst = kb;  base = 1310720; }
  else if (i < 1835008) { src = vw;  dst = vb;  base = 1572864; }
  else if (i < 2621440) { src = inw; dst = inb; base = 1835008; }
  else if (i < 2883584) { src = ow;  dst = ob;  base = 2621440; }
  else                  { src = fw;  dst = fb;  base = 2883584; }
  const int j = i - base;
  const float4 v = *(const float4*)(src + (size_t)j * 4);
  bf16x4 o = {(bf16_t)v.x, (bf16_t)v.y, (bf16_t)v.z, (bf16_t)v.w};
  *(bf16x4*)(dst + (size_t)j * 4) = o;
}

// ---------------------------------------------------------------- mean over S
__global__ __launch_bounds__(256) void colmean_part(const float* __restrict__ x,
                                                    float* __restrict__ part) {
  const int b = blockIdx.y, sc = blockIdx.x;
  const float* base = x + ((size_t)b * Ss + sc * 32) * Ee;
  for (int k = 0; k < 4; ++k) {
    const int e = threadIdx.x + k * 256;
    float s = 0.f;
    for (int i = 0; i < 32; ++i) s += base[(size_t)i * Ee + e];
    part[((size_t)sc * 4 + b) * Ee + e] = s;
  }
}
__global__ __launch_bounds__(256) void colmean_fin(const float* __restrict__ part,
                                                   float* __restrict__ xm) {
  const int idx = blockIdx.x * 256 + threadIdx.x;
  const int b = idx >> 10, e = idx & 1023;
  float s = 0.f;
  for (int sc = 0; sc < 32; ++sc) s += part[((size_t)sc * 4 + b) * Ee + e];
  xm[idx] = s * (1.0f / 1024.0f);
}

// ---------------------------------------------------------------- h = relu(xmean @ w1^T + b1)
__global__ __launch_bounds__(256) void hgemm(const float* __restrict__ xm,
                                             const float* __restrict__ w1,
                                             const float* __restrict__ b1,
                                             float* __restrict__ hout) {
  __shared__ float xl[4 * 1024];
  for (int i = threadIdx.x; i < 4096; i += 256) xl[i] = xm[i];
  __syncthreads();
  const int j = blockIdx.x * 64 + (threadIdx.x >> 2);
  const int b = threadIdx.x & 3;
  const float* wr = w1 + (size_t)j * Ee;
  const float* xr = xl + b * 1024;
  float s = 0.f;
  for (int e = 0; e < 1024; ++e) s += xr[e] * wr[e];
  s += b1[j];
  hout[b * 1024 + j] = fmaxf(s, 0.f);
}

// ---------------------------------------------------------------- phase = cos(h @ w2^T + b2)
__global__ __launch_bounds__(128) void phasek(const float* __restrict__ hin,
                                              const float* __restrict__ w2,
                                              const float* __restrict__ b2,
                                              float* __restrict__ ph) {
  const int t = threadIdx.x;
  const int b = t >> 5, hh = t & 31;
  const float* hr = hin + b * 1024;
  const float* wr = w2 + (size_t)hh * Ee;
  float s = 0.f;
  for (int j = 0; j < 1024; ++j) s += hr[j] * wr[j];
  ph[t] = cosf(s + b2[hh]);
}

// ---------------------------------------------------------------- GEMM: C = A @ Bt^T + bias (+epilogue)
// MODE 0: bf16 | 1: *phase then bf16 | 2: +resid then bf16 | 3: fp32
template <int MODE>
__global__ __launch_bounds__(256) void gemm_bt(const bf16_t* __restrict__ A,
                                               const bf16_t* __restrict__ Bt,
                                               const float* __restrict__ bias,
                                               void* __restrict__ Cout,
                                               const float* __restrict__ phase,
                                               const bf16_t* __restrict__ resid,
                                               int K, int lda, int ldb, int ldc) {
  __shared__ bf16_t As[128 * 32];
  __shared__ bf16_t Bs[128 * 32];
  const int tid = threadIdx.x;
  const int w = tid >> 6, lane = tid & 63;
  const int m0 = blockIdx.y * 128, n0 = blockIdx.x * 128;
  const int wr = (w >> 1) * 64, wc = (w & 1) * 64;
  const int r_ld = lane >> 2, c_ld = (lane & 3) * 8;
  const int rr = lane & 15, kk8 = (lane >> 4) * 8;
  f32x4 acc[4][4];
#pragma unroll
  for (int m = 0; m < 4; ++m)
#pragma unroll
    for (int n = 0; n < 4; ++n) acc[m][n] = f32x4{0.f, 0.f, 0.f, 0.f};

  for (int kt = 0; kt < K; kt += 32) {
#pragma unroll
    for (int j = 0; j < 2; ++j) {
      const int r0 = w * 16 + j * 64;
      gl_lds16(A + (size_t)(m0 + r0 + r_ld) * lda + kt + c_ld, &As[r0 * 32]);
      gl_lds16(Bt + (size_t)(n0 + r0 + r_ld) * ldb + kt + c_ld, &Bs[r0 * 32]);
    }
    __syncthreads();
    bf16x8 af[4], bfr[4];
#pragma unroll
    for (int m = 0; m < 4; ++m) af[m] = *(const bf16x8*)&As[(wr + m * 16 + rr) * 32 + kk8];
#pragma unroll
    for (int n = 0; n < 4; ++n) bfr[n] = *(const bf16x8*)&Bs[(wc + n * 16 + rr) * 32 + kk8];
#pragma unroll
    for (int m = 0; m < 4; ++m)
#pragma unroll
      for (int n = 0; n < 4; ++n)
        acc[m][n] = __builtin_amdgcn_mfma_f32_16x16x32_bf16(af[m], bfr[n], acc[m][n], 0, 0, 0);
    __syncthreads();
  }

  const int rr4 = (lane >> 4) * 4, cc = lane & 15;
#pragma unroll
  for (int m = 0; m < 4; ++m) {
#pragma unroll
    for (int n = 0; n < 4; ++n) {
      const int gr0 = m0 + wr + m * 16 + rr4;
      const int gc = n0 + wc + n * 16 + cc;
      const float bb = bias[gc];
#pragma unroll
      for (int i = 0; i < 4; ++i) {
        const size_t idx = (size_t)(gr0 + i) * ldc + gc;
        float v = acc[m][n][i] + bb;
        if constexpr (MODE == 1) v *= phase[(((gr0 + i) >> 10) << 5) + (gc >> 5)];
        if constexpr (MODE == 2) v += (float)resid[idx];
        if constexpr (MODE == 3) ((float*)Cout)[idx] = v;
        else ((bf16_t*)Cout)[idx] = (bf16_t)v;
      }
    }
  }
}

// ---------------------------------------------------------------- fused attention
// 512 thr = 8 waves, 128 q-rows per block, one bh per blockIdx.y.
// LDS: K in 4 padded k-planes (conflict-free b128), Vt padded rows, per-wave fp32 P tile.
// WRITE_P=1: 2-pass, writes normalized fp32 P to Pout (coalesced from LDS tile) + fused PV.
// WRITE_P=0: 1-pass online-softmax flash (no P materialization).
static constexpr int K_PLANE_B = 16400;           // 1025*16 bytes per k-plane
static constexpr int V_OFF_B   = 4 * K_PLANE_B;   // 65600
static constexpr int V_ROW_B   = 2064;            // 1032 elems
static constexpr int P_OFF_B   = V_OFF_B + 32 * V_ROW_B;  // 131648
static constexpr int P_WAVE_B  = 16 * 36 * 4;     // 2304
static constexpr int ATTN_LDS  = P_OFF_B + 8 * P_WAVE_B;  // 150080

template <int WRITE_P>
__global__ __launch_bounds__(512) void attn_fused(const bf16_t* __restrict__ Qm,
                                                  const bf16_t* __restrict__ Km, int rs,
                                                  const bf16_t* __restrict__ Vt,
                                                  float* __restrict__ Pout,
                                                  bf16_t* __restrict__ ctx, float scale) {
  extern __shared__ char smem[];
  char* Kl = smem;
  char* Vl = smem + V_OFF_B;
  float* Pt = (float*)(smem + P_OFF_B);
  const int tid = threadIdx.x, lane = tid & 63, w = tid >> 6;
  const int g = lane >> 4, r = lane & 15;
  const int bh = blockIdx.y, b = bh >> 5, h = bh & 31;

  // --- stage K: wave w -> plane pg=w>>1, half hh=w&1 (512 rows)
  {
    const bf16_t* Kbase = Km + (size_t)b * Ss * rs + h * 32;
    const int pg = w >> 1, hh = w & 1;
#pragma unroll
    for (int c = 0; c < 8; ++c) {
      const int row0 = hh * 512 + c * 64;
      gl_lds16(Kbase + (size_t)(row0 + lane) * rs + pg * 8, Kl + pg * K_PLANE_B + row0 * 16);
    }
  }
  // --- stage Vt: wave w -> d-rows 4w..4w+3
  {
    const bf16_t* vsrc = Vt + (size_t)bh * (Dd * Ss);
#pragma unroll
    for (int rr2 = 0; rr2 < 4; ++rr2) {
      const int row = w * 4 + rr2;
#pragma unroll
      for (int c = 0; c < 2; ++c)
        gl_lds16(vsrc + (size_t)row * Ss + c * 512 + lane * 8, Vl + row * V_ROW_B + c * 1024);
    }
  }
  const int qrow0 = blockIdx.x * 128 + w * 16;
  const bf16_t* Qbase = Qm + (size_t)b * Ss * rs + h * 32;
  const bf16x8 af = *(const bf16x8*)(Qbase + (size_t)(qrow0 + r) * rs + g * 8);
  __syncthreads();

  float* myPt = Pt + w * (16 * 36);
  float m_[4], l_[4];
#pragma unroll
  for (int i = 0; i < 4; ++i) { m_[i] = -1e30f; l_[i] = 0.f; }
  const f32x4 zero = {0.f, 0.f, 0.f, 0.f};
  f32x4 acc[2] = {zero, zero};

  if constexpr (WRITE_P) {
    // pass 1: stats
    for (int kt = 0; kt < 16; ++kt) {
      f32x4 s[4];
#pragma unroll
      for (int n = 0; n < 4; ++n) {
        const int key = kt * 64 + n * 16 + r;
        const bf16x8 kf = *(const bf16x8*)(Kl + g * K_PLANE_B + key * 16);
        s[n] = __builtin_amdgcn_mfma_f32_16x16x32_bf16(af, kf, zero, 0, 0, 0);
      }
#pragma unroll
      for (int n = 0; n < 4; ++n)
#pragma unroll
        for (int i = 0; i < 4; ++i) s[n][i] *= scale;
#pragma unroll
      for (int i = 0; i < 4; ++i) {
        float tm = fmaxf(fmaxf(s[0][i], s[1][i]), fmaxf(s[2][i], s[3][i]));
        tm = fmaxf(tm, __shfl_xor(tm, 1));
        tm = fmaxf(tm, __shfl_xor(tm, 2));
        tm = fmaxf(tm, __shfl_xor(tm, 4));
        tm = fmaxf(tm, __shfl_xor(tm, 8));
        const float nm = fmaxf(m_[i], tm);
        float ps = __expf(s[0][i] - nm) + __expf(s[1][i] - nm) +
                   __expf(s[2][i] - nm) + __expf(s[3][i] - nm);
        ps += __shfl_xor(ps, 1);
        ps += __shfl_xor(ps, 2);
        ps += __shfl_xor(ps, 4);
        ps += __shfl_xor(ps, 8);
        l_[i] = l_[i] * __expf(m_[i] - nm) + ps;
        m_[i] = nm;
      }
    }
    float rinv[4];
#pragma unroll
    for (int i = 0; i < 4; ++i) rinv[i] = 1.0f / l_[i];

    // pass 2: recompute scores -> normalized P (LDS tile) -> global write + fused PV
    const size_t pb = (size_t)bh * Ss * Ss;
    for (int kt = 0; kt < 16; ++kt) {
      f32x4 s[4];
#pragma unroll
      for (int n = 0; n < 4; ++n) {
        const int key = kt * 64 + n * 16 + r;
        const bf16x8 kf = *(const bf16x8*)(Kl + g * K_PLANE_B + key * 16);
        s[n] = __builtin_amdgcn_mfma_f32_16x16x32_bf16(af, kf, zero, 0, 0, 0);
      }
#pragma unroll
      for (int c = 0; c < 2; ++c) {
#pragma unroll
        for (int n2 = 0; n2 < 2; ++n2) {
          const int n = 2 * c + n2;
#pragma unroll
          for (int i = 0; i < 4; ++i) {
            const float p = __expf(s[n][i] * scale - m_[i]) * rinv[i];
            myPt[(4 * g + i) * 36 + n2 * 16 + r] = p;
          }
        }
        // PV A-fragment (fp32 tile -> bf16)
        const f32x4 lo = *(const f32x4*)&myPt[r * 36 + g * 8];
        const f32x4 hi = *(const f32x4*)&myPt[r * 36 + g * 8 + 4];
        const bf16x8 pa = {(bf16_t)lo[0], (bf16_t)lo[1], (bf16_t)lo[2], (bf16_t)lo[3],
                           (bf16_t)hi[0], (bf16_t)hi[1], (bf16_t)hi[2], (bf16_t)hi[3]};
#pragma unroll
        for (int n = 0; n < 2; ++n) {
          const bf16x8 vf = *(const bf16x8*)(Vl + (n * 16 + r) * V_ROW_B +
                                             (kt * 64 + c * 32 + g * 8) * 2);
          acc[n] = __builtin_amdgcn_mfma_f32_16x16x32_bf16(pa, vf, acc[n], 0, 0, 0);
        }
        // coalesced global P write (float4, 16 rows x 32 keys per chunk)
        const int pr = lane >> 3, pc = (lane & 7) * 4;
        const float4 w0 = *(const float4*)&myPt[pr * 36 + pc];
        const float4 w1 = *(const float4*)&myPt[(pr + 8) * 36 + pc];
        const size_t gbase = pb + (size_t)(qrow0 + pr) * Ss + kt * 64 + c * 32 + pc;
        *(float4*)&Pout[gbase] = w0;
        *(float4*)&Pout[gbase + (size_t)8 * Ss] = w1;
      }
    }
  } else {
    // 1-pass online flash
    for (int kt = 0; kt < 16; ++kt) {
      f32x4 s[4];
#pragma unroll
      for (int n = 0; n < 4; ++n) {
        const int key = kt * 64 + n * 16 + r;
        const bf16x8 kf = *(const bf16x8*)(Kl + g * K_PLANE_B + key * 16);
        s[n] = __builtin_amdgcn_mfma_f32_16x16x32_bf16(af, kf, zero, 0, 0, 0);
      }
#pragma unroll
      for (int n = 0; n < 4; ++n)
#pragma unroll
        for (int i = 0; i < 4; ++i) s[n][i] *= scale;
#pragma unroll
      for (int i = 0; i < 4; ++i) {
        float tm = fmaxf(fmaxf(s[0][i], s[1][i]), fmaxf(s[2][i], s[3][i]));
        tm = fmaxf(tm, __shfl_xor(tm, 1));
        tm = fmaxf(tm, __shfl_xor(tm, 2));
        tm = fmaxf(tm, __shfl_xor(tm, 4));
        tm = fmaxf(tm, __shfl_xor(tm, 8));
        const float nm = fmaxf(m_[i], tm);
        const float f = __expf(m_[i] - nm);
        m_[i] = nm;
        float ps = 0.f;
#pragma unroll
        for (int n = 0; n < 4; ++n) {
          const float pn = __expf(s[n][i] - nm);
          s[n][i] = pn;
          ps += pn;
        }
        ps += __shfl_xor(ps, 1);
        ps += __shfl_xor(ps, 2);
        ps += __shfl_xor(ps, 4);
        ps += __shfl_xor(ps, 8);
        l_[i] = l_[i] * f + ps;
        acc[0][i] *= f;
        acc[1][i] *= f;
      }
#pragma unroll
      for (int c = 0; c < 2; ++c) {
#pragma unroll
        for (int n2 = 0; n2 < 2; ++n2)
#pragma unroll
          for (int i = 0; i < 4; ++i)
            myPt[(4 * g + i) * 36 + n2 * 16 + r] = s[2 * c + n2][i];
        const f32x4 lo = *(const f32x4*)&myPt[r * 36 + g * 8];
        const f32x4 hi = *(const f32x4*)&myPt[r * 36 + g * 8 + 4];
        const bf16x8 pa = {(bf16_t)lo[0], (bf16_t)lo[1], (bf16_t)lo[2], (bf16_t)lo[3],
                           (bf16_t)hi[0], (bf16_t)hi[1], (bf16_t)hi[2], (bf16_t)hi[3]};
#pragma unroll
        for (int n = 0; n < 2; ++n) {
          const bf16x8 vf = *(const bf16x8*)(Vl + (n * 16 + r) * V_ROW_B +
                                             (kt * 64 + c * 32 + g * 8) * 2);
          acc[n] = __builtin_amdgcn_mfma_f32_16x16x32_bf16(pa, vf, acc[n], 0, 0, 0);
        }
      }
    }
    float rinv[4];
#pragma unroll
    for (int i = 0; i < 4; ++i) rinv[i] = 1.0f / l_[i];
#pragma unroll
    for (int n = 0; n < 2; ++n)
#pragma unroll
      for (int i = 0; i < 4; ++i) acc[n][i] *= rinv[i];
  }

  // --- ctx store
#pragma unroll
  for (int n = 0; n < 2; ++n)
#pragma unroll
    for (int i = 0; i < 4; ++i) {
      const int q = qrow0 + 4 * g + i;
      ctx[((size_t)b * Ss + q) * Ee + h * 32 + n * 16 + r] = (bf16_t)acc[n][i];
    }
}

// ---------------------------------------------------------------- V transpose: [token, e] -> [bh][d][s]
__global__ __launch_bounds__(256) void transpose_v(const bf16_t* __restrict__ src, int rs,
                                                   bf16_t* __restrict__ dst) {
  __shared__ bf16_t buf[128 * 33];
  const int bh = blockIdx.y, b = bh >> 5, h = bh & 31;
  const int s0 = blockIdx.x * 128;
  const bf16_t* in = src + ((size_t)b * Ss + s0) * rs + h * 32;
  for (int e = threadIdx.x; e < 128 * 32; e += 256) {
    const int s = e >> 5, d = e & 31;
    buf[s * 33 + d] = in[(size_t)s * rs + d];
  }
  __syncthreads();
  bf16_t* out = dst + (size_t)bh * (Dd * Ss) + s0;
  for (int e = threadIdx.x; e < 128 * 32; e += 256) {
    const int d = e >> 7, s = e & 127;
    out[(size_t)d * Ss + s] = buf[s * 33 + d];
  }
}

// ================================================================ launcher
extern "C" void kernel_launch(void* const* d_in, const int* in_sizes, int n_in,
                              void* d_out, int out_size, void* d_ws, size_t ws_size,
                              hipStream_t stream) {
  const float* x     = (const float*)d_in[0];
  const float* q_w   = (const float*)d_in[1];
  const float* q_b   = (const float*)d_in[2];
  const float* k_w   = (const float*)d_in[3];
  const float* k_b   = (const float*)d_in[4];
  const float* v_w   = (const float*)d_in[5];
  const float* v_b   = (const float*)d_in[6];
  const float* ph_w1 = (const float*)d_in[7];
  const float* ph_b1 = (const float*)d_in[8];
  const float* ph_w2 = (const float*)d_in[9];
  const float* ph_b2 = (const float*)d_in[10];
  const float* in_w  = (const float*)d_in[11];
  const float* in_b  = (const float*)d_in[12];
  const float* out_w = (const float*)d_in[13];
  const float* out_b = (const float*)d_in[14];
  const float* fin_w = (const float*)d_in[15];
  const float* fin_b = (const float*)d_in[16];

  float* outp = (float*)d_out;
  float* attn_out = outp + (size_t)Ntok * Ee;

  char* ws = (char*)d_ws;
  size_t off = 0;
  auto alloc = [&](size_t bytes) -> void* {
    void* p = ws + off;
    off += (bytes + 255) & ~(size_t)255;
    return p;
  };
  bf16_t* x_bf = (bf16_t*)alloc((size_t)Ntok * Ee * 2);
  bf16_t* wq   = (bf16_t*)alloc((size_t)Ee * Ee * 2);
  bf16_t* wk   = (bf16_t*)alloc((size_t)Ee * Ee * 2);
  bf16_t* wv   = (bf16_t*)alloc((size_t)Ee * Ee * 2);
  bf16_t* win  = (bf16_t*)alloc((size_t)E3 * Ee * 2);
  bf16_t* wout = (bf16_t*)alloc((size_t)Ee * Ee * 2);
  bf16_t* wfin = (bf16_t*)alloc((size_t)Ee * Ee * 2);
  bf16_t* Qb   = (bf16_t*)alloc((size_t)Ntok * Ee * 2);
  bf16_t* Kb   = (bf16_t*)alloc((size_t)Ntok * Ee * 2);
  bf16_t* Vb   = (bf16_t*)alloc((size_t)Ntok * Ee * 2);
  bf16_t* Vt   = (bf16_t*)alloc((size_t)Bb * Hh * Dd * Ss * 2);
  bf16_t* ctx  = (bf16_t*)alloc((size_t)Ntok * Ee * 2);
  bf16_t* qkv2 = (bf16_t*)alloc((size_t)Ntok * E3 * 2);
  bf16_t* v2t  = (bf16_t*)alloc((size_t)Bb * Hh * Dd * Ss * 2);
  bf16_t* ctx2 = (bf16_t*)alloc((size_t)Ntok * Ee * 2);
  bf16_t* yb   = (bf16_t*)alloc((size_t)Ntok * Ee * 2);
  float* part  = (float*)alloc((size_t)32 * 4 * 1024 * 4);
  float* xmean = (float*)alloc(4096 * 4);
  float* hb    = (float*)alloc(4096 * 4);
  float* phase = (float*)alloc(128 * 4);

  // opt-in to >64KB dynamic LDS for the fused attention kernels
  hipFuncSetAttribute((const void*)attn_fused<1>,
                      hipFuncAttributeMaxDynamicSharedMemorySize, ATTN_LDS);
  hipFuncSetAttribute((const void*)attn_fused<0>,
                      hipFuncAttributeMaxDynamicSharedMemorySize, ATTN_LDS);

  // --- conversions (single kernel)
  conv_all<<<12288, 256, 0, stream>>>(x, q_w, k_w, v_w, in_w, out_w, fin_w,
                                      x_bf, wq, wk, wv, win, wout, wfin);

  // --- phase chain (fp32)
  colmean_part<<<dim3(32, 4), 256, 0, stream>>>(x, part);
  colmean_fin<<<16, 256, 0, stream>>>(part, xmean);
  hgemm<<<16, 256, 0, stream>>>(xmean, ph_w1, ph_b1, hb);
  phasek<<<1, 128, 0, stream>>>(hb, ph_w2, ph_b2, phase);

  // --- projections (Q,K get phase fused in epilogue)
  gemm_bt<1><<<dim3(8, 32), 256, 0, stream>>>(x_bf, wq, q_b, Qb, phase, nullptr, 1024, Ee, Ee, Ee);
  gemm_bt<1><<<dim3(8, 32), 256, 0, stream>>>(x_bf, wk, k_b, Kb, phase, nullptr, 1024, Ee, Ee, Ee);
  gemm_bt<0><<<dim3(8, 32), 256, 0, stream>>>(x_bf, wv, v_b, Vb, nullptr, nullptr, 1024, Ee, Ee, Ee);
  transpose_v<<<dim3(8, 128), 256, 0, stream>>>(Vb, Ee, Vt);

  // --- attention 1 (fused scores+softmax+P-write+PV)
  attn_fused<1><<<dim3(8, 128), 512, ATTN_LDS, stream>>>(Qb, Kb, Ee, Vt, attn_out, ctx, SCALE);

  // --- MHA on context
  gemm_bt<0><<<dim3(24, 32), 256, 0, stream>>>(ctx, win, in_b, qkv2, nullptr, nullptr, 1024, Ee, Ee, E3);
  transpose_v<<<dim3(8, 128), 256, 0, stream>>>(qkv2 + 2048, E3, v2t);
  // --- attention 2 (flash, no P materialization)
  attn_fused<0><<<dim3(8, 128), 512, ATTN_LDS, stream>>>(qkv2, qkv2 + 1024, E3, v2t, nullptr, ctx2, SCALE);

  // --- out_proj with fused residual, then final
  gemm_bt<2><<<dim3(8, 32), 256, 0, stream>>>(ctx2, wout, out_b, yb, nullptr, ctx, 1024, Ee, Ee, Ee);
  gemm_bt<3><<<dim3(8, 32), 256, 0, stream>>>(yb, wfin, fin_b, outp, nullptr, nullptr, 1024, Ee, Ee, Ee);
}

// Round 3
// 542.156 us; speedup vs baseline: 1.5053x; 1.0686x over previous
//
#include <hip/hip_runtime.h>
#include <hip/hip_bf16.h>
#include <cstdint>
#include <cstddef>

typedef __bf16 bf16_t;
typedef __bf16 bf16x8 __attribute__((ext_vector_type(8)));
typedef __bf16 bf16x4 __attribute__((ext_vector_type(4)));
typedef float  f32x4  __attribute__((ext_vector_type(4)));

static constexpr int Bb = 4, Ss = 1024, Ee = 1024, Hh = 32, Dd = 32;
static constexpr int Ntok = Bb * Ss;   // 4096
static constexpr int E3   = 3 * Ee;    // 3072
static constexpr float SCALE = 0.17677669529663687f; // 1/sqrt(32)

__device__ __forceinline__ void gl_lds16(const void* g, void* l) {
  __builtin_amdgcn_global_load_lds(
      (const __attribute__((address_space(1))) void*)g,
      (__attribute__((address_space(3))) void*)l, 16, 0, 0);
}

// ---------------------------------------------------------------- fused f32->bf16 conversions
__global__ __launch_bounds__(256) void conv_all(const float* __restrict__ x,  const float* __restrict__ qw,
                                                const float* __restrict__ kw, const float* __restrict__ vw,
                                                const float* __restrict__ inw,const float* __restrict__ ow,
                                                const float* __restrict__ fw,
                                                bf16_t* xb, bf16_t* qb, bf16_t* kb, bf16_t* vb,
                                                bf16_t* inb, bf16_t* ob, bf16_t* fb) {
  const int i = blockIdx.x * 256 + threadIdx.x;
  const float* src; bf16_t* dst; int base;
  if      (i < 1048576) { src = x;   dst = xb;  base = 0; }
  else if (i < 1310720) { src = qw;  dst = qb;  base = 1048576; }
  else if (i < 1572864) { src = kw;  dst = kb;  base = 1310720; }
  else if (i < 1835008) { src = vw;  dst = vb;  base = 1572864; }
  else if (i < 2621440) { src = inw; dst = inb; base = 1835008; }
  else if (i < 2883584) { src = ow;  dst = ob;  base = 2621440; }
  else                  { src = fw;  dst = fb;  base = 2883584; }
  const int j = i - base;
  const float4 v = *(const float4*)(src + (size_t)j * 4);
  bf16x4 o = {(bf16_t)v.x, (bf16_t)v.y, (bf16_t)v.z, (bf16_t)v.w};
  *(bf16x4*)(dst + (size_t)j * 4) = o;
}

// ---------------------------------------------------------------- bias concat q_b|k_b|v_b
__global__ __launch_bounds__(256) void prepb(const float* __restrict__ qb, const float* __restrict__ kb,
                                             const float* __restrict__ vb, float* __restrict__ o) {
  const int i = blockIdx.x * 256 + threadIdx.x;
  o[i] = (i < 1024) ? qb[i] : (i < 2048) ? kb[i - 1024] : vb[i - 2048];
}

// ---------------------------------------------------------------- bias_c[n] = fin_b[n] + sum_j fin_w[n][j]*out_b[j]
__global__ __launch_bounds__(256) void biasck(const float* __restrict__ fw, const float* __restrict__ ob,
                                              const float* __restrict__ fb, float* __restrict__ bc) {
  const int t = threadIdx.x;
  const int n = blockIdx.x * 64 + (t >> 2), p = t & 3;
  const float* row = fw + (size_t)n * 1024 + p * 256;
  const float* obp = ob + p * 256;
  float s = 0.f;
  for (int j = 0; j < 256; ++j) s += row[j] * obp[j];
  s += __shfl_xor(s, 1);
  s += __shfl_xor(s, 2);
  if (p == 0) bc[n] = s + fb[n];
}

// ---------------------------------------------------------------- mean over S
__global__ __launch_bounds__(256) void colmean_part(const float* __restrict__ x,
                                                    float* __restrict__ part) {
  const int b = blockIdx.y, sc = blockIdx.x;
  const float* base = x + ((size_t)b * Ss + sc * 32) * Ee;
  for (int k = 0; k < 4; ++k) {
    const int e = threadIdx.x + k * 256;
    float s = 0.f;
    for (int i = 0; i < 32; ++i) s += base[(size_t)i * Ee + e];
    part[((size_t)sc * 4 + b) * Ee + e] = s;
  }
}
__global__ __launch_bounds__(256) void colmean_fin(const float* __restrict__ part,
                                                   float* __restrict__ xm) {
  const int idx = blockIdx.x * 256 + threadIdx.x;
  const int b = idx >> 10, e = idx & 1023;
  float s = 0.f;
  for (int sc = 0; sc < 32; ++sc) s += part[((size_t)sc * 4 + b) * Ee + e];
  xm[idx] = s * (1.0f / 1024.0f);
}

// ---------------------------------------------------------------- h = relu(xmean @ w1^T + b1)
__global__ __launch_bounds__(256) void hgemm(const float* __restrict__ xm,
                                             const float* __restrict__ w1,
                                             const float* __restrict__ b1,
                                             float* __restrict__ hout) {
  __shared__ float xl[4 * 1024];
  for (int i = threadIdx.x; i < 4096; i += 256) xl[i] = xm[i];
  __syncthreads();
  const int j = blockIdx.x * 64 + (threadIdx.x >> 2);
  const int b = threadIdx.x & 3;
  const float* wr = w1 + (size_t)j * Ee;
  const float* xr = xl + b * 1024;
  float s = 0.f;
  for (int e = 0; e < 1024; ++e) s += xr[e] * wr[e];
  s += b1[j];
  hout[b * 1024 + j] = fmaxf(s, 0.f);
}

// ---------------------------------------------------------------- phase = cos(h @ w2^T + b2)
__global__ __launch_bounds__(128) void phasek(const float* __restrict__ hin,
                                              const float* __restrict__ w2,
                                              const float* __restrict__ b2,
                                              float* __restrict__ ph) {
  const int t = threadIdx.x;
  const int b = t >> 5, hh = t & 31;
  const float* hr = hin + b * 1024;
  const float* wr = w2 + (size_t)hh * Ee;
  float s = 0.f;
  for (int j = 0; j < 1024; ++j) s += hr[j] * wr[j];
  ph[t] = cosf(s + b2[hh]);
}

// ---------------------------------------------------------------- bf16 1024x1024 transpose (out[k][j] = in[j][k])
__global__ __launch_bounds__(256) void transpose1024(const bf16_t* __restrict__ in,
                                                     bf16_t* __restrict__ out) {
  __shared__ bf16_t t[64][72];
  const int jt = threadIdx.x >> 2, k16 = (threadIdx.x & 3) * 16;
  const int r0 = blockIdx.y * 64, c0 = blockIdx.x * 64;
  const bf16x8 a = *(const bf16x8*)(in + (size_t)(r0 + jt) * 1024 + c0 + k16);
  const bf16x8 b = *(const bf16x8*)(in + (size_t)(r0 + jt) * 1024 + c0 + k16 + 8);
  *(bf16x8*)&t[jt][k16] = a;
  *(bf16x8*)&t[jt][k16 + 8] = b;
  __syncthreads();
  bf16x8 v0, v1;
#pragma unroll
  for (int m = 0; m < 8; ++m) v0[m] = t[k16 + m][jt];
#pragma unroll
  for (int m = 0; m < 8; ++m) v1[m] = t[k16 + 8 + m][jt];
  *(bf16x8*)(out + (size_t)(c0 + jt) * 1024 + r0 + k16) = v0;
  *(bf16x8*)(out + (size_t)(c0 + jt) * 1024 + r0 + k16 + 8) = v1;
}

// ---------------------------------------------------------------- GEMM: C = A @ Bt^T + bias (+epilogue)
// MODE 0: bf16 | 3: fp32 | 4: bf16 * phase(3072-layout, cols<2048) | 5: fp32, split-K (A2/Bt2 for k>=1024)
template <int MODE>
__global__ __launch_bounds__(256) void gemm_bt(const bf16_t* __restrict__ A,
                                               const bf16_t* __restrict__ A2,
                                               const bf16_t* __restrict__ Bt,
                                               const bf16_t* __restrict__ Bt2,
                                               const float* __restrict__ bias,
                                               void* __restrict__ Cout,
                                               const float* __restrict__ phase,
                                               int K, int lda, int ldb, int ldc) {
  __shared__ bf16_t As[128 * 32];
  __shared__ bf16_t Bs[128 * 32];
  const int tid = threadIdx.x;
  const int w = tid >> 6, lane = tid & 63;
  // XCD-aware swizzle (nwg % 8 == 0 for all grids used)
  const int nwg = gridDim.x * gridDim.y;
  int flat = blockIdx.y * gridDim.x + blockIdx.x;
  flat = (flat & 7) * (nwg >> 3) + (flat >> 3);
  const int m0 = (flat / gridDim.x) * 128, n0 = (flat % gridDim.x) * 128;
  const int wr = (w >> 1) * 64, wc = (w & 1) * 64;
  const int r_ld = lane >> 2, c_ld = (lane & 3) * 8;
  const int rr = lane & 15, kk8 = (lane >> 4) * 8;
  f32x4 acc[4][4];
#pragma unroll
  for (int m = 0; m < 4; ++m)
#pragma unroll
    for (int n = 0; n < 4; ++n) acc[m][n] = f32x4{0.f, 0.f, 0.f, 0.f};

  for (int kt = 0; kt < K; kt += 32) {
    const bf16_t* Ak = A;
    const bf16_t* Bk = Bt;
    int kk = kt;
    if constexpr (MODE == 5) {
      if (kt >= 1024) { Ak = A2; Bk = Bt2; kk = kt - 1024; }
    }
#pragma unroll
    for (int j = 0; j < 2; ++j) {
      const int r0 = w * 16 + j * 64;
      gl_lds16(Ak + (size_t)(m0 + r0 + r_ld) * lda + kk + c_ld, &As[r0 * 32]);
      gl_lds16(Bk + (size_t)(n0 + r0 + r_ld) * ldb + kk + c_ld, &Bs[r0 * 32]);
    }
    __syncthreads();
    bf16x8 af[4], bfr[4];
#pragma unroll
    for (int m = 0; m < 4; ++m) af[m] = *(const bf16x8*)&As[(wr + m * 16 + rr) * 32 + kk8];
#pragma unroll
    for (int n = 0; n < 4; ++n) bfr[n] = *(const bf16x8*)&Bs[(wc + n * 16 + rr) * 32 + kk8];
#pragma unroll
    for (int m = 0; m < 4; ++m)
#pragma unroll
      for (int n = 0; n < 4; ++n)
        acc[m][n] = __builtin_amdgcn_mfma_f32_16x16x32_bf16(af[m], bfr[n], acc[m][n], 0, 0, 0);
    __syncthreads();
  }

  const int rr4 = (lane >> 4) * 4, cc = lane & 15;
#pragma unroll
  for (int m = 0; m < 4; ++m) {
#pragma unroll
    for (int n = 0; n < 4; ++n) {
      const int gr0 = m0 + wr + m * 16 + rr4;
      const int gc = n0 + wc + n * 16 + cc;
      const float bb = bias ? bias[gc] : 0.f;
#pragma unroll
      for (int i = 0; i < 4; ++i) {
        const size_t idx = (size_t)(gr0 + i) * ldc + gc;
        float v = acc[m][n][i] + bb;
        if constexpr (MODE == 4) {
          if (gc < 2048) v *= phase[(((gr0 + i) >> 10) << 5) + ((gc >> 5) & 31)];
        }
        if constexpr (MODE == 3 || MODE == 5) ((float*)Cout)[idx] = v;
        else ((bf16_t*)Cout)[idx] = (bf16_t)v;
      }
    }
  }
}

// ---------------------------------------------------------------- fused attention (swapped QK^T, no-max softmax)
// 512 thr = 8 waves, 128 q-rows/block. s[n] = mfma(K,Q) -> S^T: lane(g,r) holds
// keys {kt*64+n*16+4g+i} for q = qrow0+r. Sum-reduce = per-lane acc + 2 shfl at end.
// WRITE_P=1: pass1 sums, pass2 writes normalized fp32 P (reg-direct float4) + PV.
// WRITE_P=0: single pass, post-normalized flash.
static constexpr int K_PLANE_B = 16400;           // 1025*16 B per k-plane
static constexpr int V_OFF_B   = 4 * K_PLANE_B;   // 65600
static constexpr int V_ROW_B   = 2064;            // 1032 bf16
static constexpr int P_OFF_B   = V_OFF_B + 32 * V_ROW_B;  // 131648
static constexpr int P_WAVE_B  = 2304;            // 16 rows * 144 B (bf16 P tile / f32 ctx tile)
static constexpr int ATTN_LDS  = P_OFF_B + 8 * P_WAVE_B;  // 150080

template <int WRITE_P>
__global__ __launch_bounds__(512) void attn_fused(const bf16_t* __restrict__ Qm,
                                                  const bf16_t* __restrict__ Km, int rs,
                                                  const bf16_t* __restrict__ Vt,
                                                  float* __restrict__ Pout,
                                                  bf16_t* __restrict__ ctx, float scale) {
  extern __shared__ char smem[];
  char* Kl = smem;
  char* Vl = smem + V_OFF_B;
  const int tid = threadIdx.x, lane = tid & 63, w = tid >> 6;
  const int g = lane >> 4, r = lane & 15;
  // XCD swizzle: consecutive logical ids share bh (K/V L2 reuse)
  int flat = blockIdx.y * 8 + blockIdx.x;
  flat = (flat & 7) * 128 + (flat >> 3);
  const int bh = flat >> 3, xb = flat & 7;
  const int b = bh >> 5, h = bh & 31;
  char* myP = smem + P_OFF_B + w * P_WAVE_B;

  // --- stage K: wave w -> plane pg=w>>1, half hh=w&1
  {
    const bf16_t* Kbase = Km + (size_t)b * Ss * rs + h * 32;
    const int pg = w >> 1, hh = w & 1;
#pragma unroll
    for (int c = 0; c < 8; ++c) {
      const int row0 = hh * 512 + c * 64;
      gl_lds16(Kbase + (size_t)(row0 + lane) * rs + pg * 8, Kl + pg * K_PLANE_B + row0 * 16);
    }
  }
  // --- stage Vt: wave w -> d-rows 4w..4w+3
  {
    const bf16_t* vsrc = Vt + (size_t)bh * (Dd * Ss);
#pragma unroll
    for (int rr2 = 0; rr2 < 4; ++rr2) {
      const int row = w * 4 + rr2;
#pragma unroll
      for (int c = 0; c < 2; ++c)
        gl_lds16(vsrc + (size_t)row * Ss + c * 512 + lane * 8, Vl + row * V_ROW_B + c * 1024);
    }
  }
  const int qrow0 = xb * 128 + w * 16;
  const bf16_t* Qbase = Qm + (size_t)b * Ss * rs + h * 32;
  const bf16x8 qraw = *(const bf16x8*)(Qbase + (size_t)(qrow0 + r) * rs + g * 8);
  bf16x8 qf;  // pre-scaled Q fragment (B operand)
#pragma unroll
  for (int i = 0; i < 8; ++i) qf[i] = (bf16_t)((float)qraw[i] * scale);
  __syncthreads();

  const f32x4 zero = {0.f, 0.f, 0.f, 0.f};
  float lsum = 0.f;
  float rinv = 1.f;

  if constexpr (WRITE_P) {
    // pass 1: row sums (per-lane partial; reduce across g at end)
    for (int kt = 0; kt < 16; ++kt) {
#pragma unroll
      for (int n = 0; n < 4; ++n) {
        const int key = kt * 64 + n * 16 + r;
        const bf16x8 kf = *(const bf16x8*)(Kl + g * K_PLANE_B + key * 16);
        const f32x4 s = __builtin_amdgcn_mfma_f32_16x16x32_bf16(kf, qf, zero, 0, 0, 0);
#pragma unroll
        for (int i = 0; i < 4; ++i) lsum += __expf(fminf(s[i], 60.f));
      }
    }
    lsum += __shfl_xor(lsum, 16);
    lsum += __shfl_xor(lsum, 32);
    rinv = 1.0f / lsum;
  }

  f32x4 acc2[2] = {zero, zero};  // ctx^T: acc2[dn][i] = ctx[q=qrow0+r][d=dn*16+4g+i]
  const size_t pbase = (size_t)bh * Ss * Ss;

  for (int kt = 0; kt < 16; ++kt) {
    float p[4][4];
#pragma unroll
    for (int n = 0; n < 4; ++n) {
      const int key = kt * 64 + n * 16 + r;
      const bf16x8 kf = *(const bf16x8*)(Kl + g * K_PLANE_B + key * 16);
      const f32x4 s = __builtin_amdgcn_mfma_f32_16x16x32_bf16(kf, qf, zero, 0, 0, 0);
#pragma unroll
      for (int i = 0; i < 4; ++i) {
        float e = __expf(fminf(s[i], 60.f));
        if constexpr (WRITE_P) e *= rinv;
        else lsum += e;
        p[n][i] = e;
      }
      // stage P fragment to LDS (bf16x4, conflict-light)
      bf16x4 pw = {(bf16_t)p[n][0], (bf16_t)p[n][1], (bf16_t)p[n][2], (bf16_t)p[n][3]};
      *(bf16x4*)(myP + r * 144 + (n * 16 + g * 4) * 2) = pw;
      if constexpr (WRITE_P) {
        // reg-direct normalized P write: 4 consecutive keys per lane
        f32x4 w4 = {p[n][0], p[n][1], p[n][2], p[n][3]};
        *(f32x4*)&Pout[pbase + (size_t)(qrow0 + r) * Ss + kt * 64 + n * 16 + 4 * g] = w4;
      }
    }
    // PV: A = V^T rows (d), B = P rows (q) -> C[d][q]
#pragma unroll
    for (int c = 0; c < 2; ++c) {
      const bf16x8 pa = *(const bf16x8*)(myP + r * 144 + (c * 32 + 8 * g) * 2);
#pragma unroll
      for (int dn = 0; dn < 2; ++dn) {
        const bf16x8 vf = *(const bf16x8*)(Vl + (dn * 16 + r) * V_ROW_B +
                                           (kt * 64 + c * 32 + g * 8) * 2);
        acc2[dn] = __builtin_amdgcn_mfma_f32_16x16x32_bf16(vf, pa, acc2[dn], 0, 0, 0);
      }
    }
  }

  if constexpr (!WRITE_P) {
    lsum += __shfl_xor(lsum, 16);
    lsum += __shfl_xor(lsum, 32);
    rinv = 1.0f / lsum;
#pragma unroll
    for (int dn = 0; dn < 2; ++dn)
#pragma unroll
      for (int i = 0; i < 4; ++i) acc2[dn][i] *= rinv;
  }

  // --- ctx^T -> ctx via per-wave LDS transpose (reuse myP as float tile [16][36])
  float* Ct = (float*)myP;
#pragma unroll
  for (int dn = 0; dn < 2; ++dn)
#pragma unroll
    for (int i = 0; i < 4; ++i)
      Ct[r * 36 + dn * 16 + 4 * g + i] = acc2[dn][i];
  const int q2 = lane >> 2, pt = lane & 3;
  const f32x4 ca = *(const f32x4*)(myP + q2 * 144 + pt * 32);
  const f32x4 cb = *(const f32x4*)(myP + q2 * 144 + pt * 32 + 16);
  bf16x8 cv = {(bf16_t)ca[0], (bf16_t)ca[1], (bf16_t)ca[2], (bf16_t)ca[3],
               (bf16_t)cb[0], (bf16_t)cb[1], (bf16_t)cb[2], (bf16_t)cb[3]};
  *(bf16x8*)&ctx[((size_t)b * Ss + qrow0 + q2) * Ee + h * 32 + pt * 8] = cv;
}

// ---------------------------------------------------------------- V transpose: [token, e] -> [bh][d][s]
__global__ __launch_bounds__(256) void transpose_v(const bf16_t* __restrict__ src, int rs,
                                                   bf16_t* __restrict__ dst) {
  __shared__ bf16_t buf[128 * 33];
  const int bh = blockIdx.y, b = bh >> 5, h = bh & 31;
  const int s0 = blockIdx.x * 128;
  const bf16_t* in = src + ((size_t)b * Ss + s0) * rs + h * 32;
  for (int e = threadIdx.x; e < 128 * 32; e += 256) {
    const int s = e >> 5, d = e & 31;
    buf[s * 33 + d] = in[(size_t)s * rs + d];
  }
  __syncthreads();
  bf16_t* out = dst + (size_t)bh * (Dd * Ss) + s0;
  for (int e = threadIdx.x; e < 128 * 32; e += 256) {
    const int d = e >> 7, s = e & 127;
    out[(size_t)d * Ss + s] = buf[s * 33 + d];
  }
}

// ================================================================ launcher
extern "C" void kernel_launch(void* const* d_in, const int* in_sizes, int n_in,
                              void* d_out, int out_size, void* d_ws, size_t ws_size,
                              hipStream_t stream) {
  const float* x     = (const float*)d_in[0];
  const float* q_w   = (const float*)d_in[1];
  const float* q_b   = (const float*)d_in[2];
  const float* k_w   = (const float*)d_in[3];
  const float* k_b   = (const float*)d_in[4];
  const float* v_w   = (const float*)d_in[5];
  const float* v_b   = (const float*)d_in[6];
  const float* ph_w1 = (const float*)d_in[7];
  const float* ph_b1 = (const float*)d_in[8];
  const float* ph_w2 = (const float*)d_in[9];
  const float* ph_b2 = (const float*)d_in[10];
  const float* in_w  = (const float*)d_in[11];
  const float* in_b  = (const float*)d_in[12];
  const float* out_w = (const float*)d_in[13];
  const float* out_b = (const float*)d_in[14];
  const float* fin_w = (const float*)d_in[15];
  const float* fin_b = (const float*)d_in[16];

  float* outp = (float*)d_out;
  float* attn_out = outp + (size_t)Ntok * Ee;

  char* ws = (char*)d_ws;
  size_t off = 0;
  auto alloc = [&](size_t bytes) -> void* {
    void* p = ws + off;
    off += (bytes + 255) & ~(size_t)255;
    return p;
  };
  bf16_t* x_bf  = (bf16_t*)alloc((size_t)Ntok * Ee * 2);
  bf16_t* wqkv  = (bf16_t*)alloc((size_t)E3 * Ee * 2);    // wq|wk|wv contiguous
  bf16_t* win   = (bf16_t*)alloc((size_t)E3 * Ee * 2);
  bf16_t* wout  = (bf16_t*)alloc((size_t)Ee * Ee * 2);
  bf16_t* wfin  = (bf16_t*)alloc((size_t)Ee * Ee * 2);
  bf16_t* woutT = (bf16_t*)alloc((size_t)Ee * Ee * 2);
  bf16_t* Wc    = (bf16_t*)alloc((size_t)Ee * Ee * 2);
  bf16_t* QKVb  = (bf16_t*)alloc((size_t)Ntok * E3 * 2);
  bf16_t* Vt    = (bf16_t*)alloc((size_t)Bb * Hh * Dd * Ss * 2);
  bf16_t* ctx   = (bf16_t*)alloc((size_t)Ntok * Ee * 2);
  bf16_t* qkv2  = (bf16_t*)alloc((size_t)Ntok * E3 * 2);
  bf16_t* v2t   = (bf16_t*)alloc((size_t)Bb * Hh * Dd * Ss * 2);
  bf16_t* ctx2  = (bf16_t*)alloc((size_t)Ntok * Ee * 2);
  float* part   = (float*)alloc((size_t)32 * 4 * 1024 * 4);
  float* xmean  = (float*)alloc(4096 * 4);
  float* hb     = (float*)alloc(4096 * 4);
  float* phase  = (float*)alloc(128 * 4);
  float* qkvb   = (float*)alloc(3072 * 4);
  float* bias_c = (float*)alloc(1024 * 4);

  hipFuncSetAttribute((const void*)attn_fused<1>,
                      hipFuncAttributeMaxDynamicSharedMemorySize, ATTN_LDS);
  hipFuncSetAttribute((const void*)attn_fused<0>,
                      hipFuncAttributeMaxDynamicSharedMemorySize, ATTN_LDS);

  // --- conversions + small prep
  conv_all<<<12288, 256, 0, stream>>>(x, q_w, k_w, v_w, in_w, out_w, fin_w,
                                      x_bf, wqkv, wqkv + (size_t)Ee * Ee,
                                      wqkv + (size_t)2 * Ee * Ee, win, wout, wfin);
  prepb<<<12, 256, 0, stream>>>(q_b, k_b, v_b, qkvb);
  biasck<<<16, 256, 0, stream>>>(fin_w, out_b, fin_b, bias_c);

  // --- phase chain (fp32)
  colmean_part<<<dim3(32, 4), 256, 0, stream>>>(x, part);
  colmean_fin<<<16, 256, 0, stream>>>(part, xmean);
  hgemm<<<16, 256, 0, stream>>>(xmean, ph_w1, ph_b1, hb);
  phasek<<<1, 128, 0, stream>>>(hb, ph_w2, ph_b2, phase);

  // --- Wc = fin_w @ out_w (for out_proj+final fusion), off critical path
  transpose1024<<<dim3(16, 16), 256, 0, stream>>>(wout, woutT);
  gemm_bt<0><<<dim3(8, 8), 256, 0, stream>>>(wfin, nullptr, woutT, nullptr, nullptr,
                                             Wc, nullptr, 1024, Ee, Ee, Ee);

  // --- fused QKV projection (phase applied to Q,K cols in epilogue)
  gemm_bt<4><<<dim3(24, 32), 256, 0, stream>>>(x_bf, nullptr, wqkv, nullptr, qkvb,
                                               QKVb, phase, 1024, Ee, Ee, E3);
  transpose_v<<<dim3(8, 128), 256, 0, stream>>>(QKVb + 2048, E3, Vt);

  // --- attention 1 (P -> d_out + fused PV)
  attn_fused<1><<<dim3(8, 128), 512, ATTN_LDS, stream>>>(QKVb, QKVb + 1024, E3, Vt,
                                                         attn_out, ctx, SCALE);

  // --- MHA on context
  gemm_bt<0><<<dim3(24, 32), 256, 0, stream>>>(ctx, nullptr, win, nullptr, in_b,
                                               qkv2, nullptr, 1024, Ee, Ee, E3);
  transpose_v<<<dim3(8, 128), 256, 0, stream>>>(qkv2 + 2048, E3, v2t);
  attn_fused<0><<<dim3(8, 128), 512, ATTN_LDS, stream>>>(qkv2, qkv2 + 1024, E3, v2t,
                                                         nullptr, ctx2, SCALE);

  // --- fused out_proj+residual+final: outp = ctx2@Wc^T + ctx@fin_w^T + bias_c
  gemm_bt<5><<<dim3(8, 32), 256, 0, stream>>>(ctx2, ctx, Wc, wfin, bias_c,
                                              outp, nullptr, 2048, Ee, Ee, Ee);
}